// Round 3
// baseline (462.738 us; speedup 1.0000x reference)
//
#include <hip/hip_runtime.h>

#define B_   32
#define ICN  1152
#define OCN  10
#define IDN  8
#define ODN  16
#define NIT  5
#define EPS  1e-20f
#define OUTN (B_ * OCN * ODN)   // 5120
#define KI   3                  // input caps per block
#define NICB (ICN / KI)         // 384
#define NBG  6                  // 6 batch-groups of 6 b's (last has 2)
#define NBLK (NICB * NBG)       // 2304 one-wave blocks

__device__ __forceinline__ float4 f4_fma(const float4 a, const float4 b, const float4 c) {
  float4 r;
  r.x = fmaf(a.x, b.x, c.x);
  r.y = fmaf(a.y, b.y, c.y);
  r.z = fmaf(a.z, b.z, c.z);
  r.w = fmaf(a.w, b.w, c.w);
  return r;
}
__device__ __forceinline__ float4 f4_mul(const float4 a, const float4 b) {
  float4 r;
  r.x = a.x * b.x; r.y = a.y * b.y; r.z = a.z * b.z; r.w = a.w * b.w;
  return r;
}
__device__ __forceinline__ float4 f4_scale(const float4 a, const float s) {
  float4 r;
  r.x = a.x * s; r.y = a.y * s; r.z = a.z * s; r.w = a.w * s;
  return r;
}
__device__ __forceinline__ float f4_hsum(const float4 a) {
  return (a.x + a.y) + (a.z + a.w);
}

// ---------------------------------------------------------------------------
// One wave = 6 b's x 10 oc (lanes 60..63 idle). Each lane owns the FULL
// (b,ic,oc) chain: 8x16 weight slice in registers (128 VGPR, float4 form ->
// v_pk_fma), all NNMF math in-lane, zero shuffles in the iteration loop.
// Only alpha normalization crosses lanes (10 shfls, once per ic).
// Each block accumulates KI=3 ics into registers, then atomicAdds its 480
// floats into d_out (pre-zeroed). No LDS, no barriers, no ws.
// ---------------------------------------------------------------------------
__global__ __launch_bounds__(64, 2) void caps_main(
    const float* __restrict__ xg, const float* __restrict__ wg,
    float* __restrict__ outg) {
  const int l = threadIdx.x;
  const int bid = blockIdx.x;
  const int icb = bid % NICB;
  const int bgrp = bid / NICB;
  const int b_sub = l / OCN;          // 0..6 (6 => idle lane)
  const int oc = l % OCN;
  const int b = bgrp * 6 + b_sub;
  const bool valid = (b_sub < 6) && (b < B_);
  const int bb = valid ? b : 0;       // clamp for loads

  float4 acc[4];
#pragma unroll
  for (int j = 0; j < 4; ++j) acc[j] = make_float4(0.f, 0.f, 0.f, 0.f);

  for (int k = 0; k < KI; ++k) {
    const int ic = icb * KI + k;

    // ---- weights w[ic][oc][0..7][0..15] -> 32 float4 registers ----
    float4 w4[IDN][4];
    {
      const float* wp = wg + ((size_t)ic * OCN + oc) * (IDN * ODN);
#pragma unroll
      for (int id = 0; id < IDN; ++id) {
#pragma unroll
        for (int j = 0; j < 4; ++j)
          w4[id][j] = ((const float4*)(wp + id * ODN))[j];
      }
    }

    // ---- x[b,ic,:] normalized over id ----
    float xn[IDN];
    {
      const float* xp = xg + ((size_t)bb * ICN + ic) * IDN;
      const float4 a0 = ((const float4*)xp)[0];
      const float4 a1 = ((const float4*)xp)[1];
      xn[0] = a0.x; xn[1] = a0.y; xn[2] = a0.z; xn[3] = a0.w;
      xn[4] = a1.x; xn[5] = a1.y; xn[6] = a1.z; xn[7] = a1.w;
      float s = 0.f;
#pragma unroll
      for (int i = 0; i < IDN; ++i) s += xn[i];
      const float r = __builtin_amdgcn_rcpf(s + EPS);
#pragma unroll
      for (int i = 0; i < IDN; ++i) xn[i] *= r;
    }

    // ---- NNMF iterations, fully in-lane ----
    float4 h4[4];
#pragma unroll
    for (int j = 0; j < 4; ++j)
      h4[j] = make_float4(1.f / ODN, 1.f / ODN, 1.f / ODN, 1.f / ODN);

    for (int it = 0; it < NIT; ++it) {
      float4 hacc[4];
#pragma unroll
      for (int j = 0; j < 4; ++j) hacc[j] = make_float4(0.f, 0.f, 0.f, 0.f);
#pragma unroll
      for (int id = 0; id < IDN; ++id) {
        float4 d4 = f4_mul(h4[0], w4[id][0]);
        d4 = f4_fma(h4[1], w4[id][1], d4);
        d4 = f4_fma(h4[2], w4[id][2], d4);
        d4 = f4_fma(h4[3], w4[id][3], d4);
        const float den = f4_hsum(d4);
        const float tc = xn[id] * __builtin_amdgcn_rcpf(den + EPS);
        const float4 t4 = make_float4(tc, tc, tc, tc);
#pragma unroll
        for (int j = 0; j < 4; ++j) hacc[j] = f4_fma(w4[id][j], t4, hacc[j]);
      }
      float4 s4 = make_float4(0.f, 0.f, 0.f, 0.f);
#pragma unroll
      for (int j = 0; j < 4; ++j) { h4[j] = f4_mul(h4[j], hacc[j]); s4 = f4_fma(h4[j], make_float4(1.f,1.f,1.f,1.f), s4); }
      const float r = __builtin_amdgcn_rcpf(f4_hsum(s4) + EPS);
      const float4 r4 = make_float4(r, r, r, r);
#pragma unroll
      for (int j = 0; j < 4; ++j) h4[j] = f4_mul(h4[j], r4);
    }

    // ---- alpha = sum_id dot(h, w[id]) * xn[id], normalized over oc ----
    float ap = 0.f;
#pragma unroll
    for (int id = 0; id < IDN; ++id) {
      float4 d4 = f4_mul(h4[0], w4[id][0]);
      d4 = f4_fma(h4[1], w4[id][1], d4);
      d4 = f4_fma(h4[2], w4[id][2], d4);
      d4 = f4_fma(h4[3], w4[id][3], d4);
      ap = fmaf(f4_hsum(d4), xn[id], ap);
    }
    float asum = 0.f;
    const int gbase = b_sub * OCN;
#pragma unroll
    for (int k2 = 0; k2 < OCN; ++k2) asum += __shfl(ap, gbase + k2, 64);
    const float an = ap * __builtin_amdgcn_rcpf(asum + EPS);
    const float4 an4 = make_float4(an, an, an, an);
#pragma unroll
    for (int j = 0; j < 4; ++j) acc[j] = f4_fma(h4[j], an4, acc[j]);
  }

  if (valid) {
    float* dst = outg + (bb * OCN + oc) * ODN;
#pragma unroll
    for (int j = 0; j < 4; ++j) {
      atomicAdd(dst + j * 4 + 0, acc[j].x);
      atomicAdd(dst + j * 4 + 1, acc[j].y);
      atomicAdd(dst + j * 4 + 2, acc[j].z);
      atomicAdd(dst + j * 4 + 3, acc[j].w);
    }
  }
}

extern "C" void kernel_launch(void* const* d_in, const int* in_sizes, int n_in,
                              void* d_out, int out_size, void* d_ws, size_t ws_size,
                              hipStream_t stream) {
  const float* x = (const float*)d_in[0];
  const float* w = (const float*)d_in[1];
  float* out = (float*)d_out;

  hipMemsetAsync(out, 0, OUTN * sizeof(float), stream);
  caps_main<<<NBLK, 64, 0, stream>>>(x, w, out);
}

// Round 4
// 152.938 us; speedup vs baseline: 3.0257x; 3.0257x over previous
//
#include <hip/hip_runtime.h>

#define B_   32
#define ICN  1152
#define OCN  10
#define IDN  8
#define ODN  16
#define ODH  8                  // od half per lane (split across lane pairs)
#define NIT  5
#define EPS  1e-20f
#define OUTN (B_ * OCN * ODN)   // 5120
#define KI   6                  // input caps accumulated per block
#define NICB (ICN / KI)         // 192
#define BGRP 11                 // ceil(32 / 3 b's per wave)
#define NBLK (NICB * BGRP)      // 2112 one-wave blocks

// swap with neighbor lane (l ^ 1) via DPP quad_perm [1,0,3,2] — VALU pipe, no DS
__device__ __forceinline__ float lane_swap1(float x) {
  int i = __builtin_bit_cast(int, x);
  int r = __builtin_amdgcn_mov_dpp(i, 0xB1, 0xF, 0xF, false);
  return __builtin_bit_cast(float, r);
}

__device__ __forceinline__ float2 f2_fma(const float2 a, const float2 b, const float2 c) {
  float2 r;
  r.x = fmaf(a.x, b.x, c.x);
  r.y = fmaf(a.y, b.y, c.y);
  return r;
}
__device__ __forceinline__ float2 f2_mul(const float2 a, const float2 b) {
  float2 r; r.x = a.x * b.x; r.y = a.y * b.y; return r;
}

// ---------------------------------------------------------------------------
// One wave = 3 (b) groups x 10 oc x 2 od-halves (lanes 60..63 idle).
// Each lane holds its 8x8 weight half-slice in registers (64 VGPR, float2
// form -> v_pk_fma_f32). Cross-half reductions are single DPP swaps.
// Block accumulates KI=6 ics into registers, then 8 atomicAdds/lane into
// pre-zeroed d_out. No LDS, no barriers, no workspace.
// Same-ic blocks are NICB apart in blockIdx (NICB*g % 8 == 0 -> same XCD).
// ---------------------------------------------------------------------------
__global__ __launch_bounds__(64, 2) void caps_main(
    const float* __restrict__ xg, const float* __restrict__ wg,
    float* __restrict__ outg) {
  const int l = threadIdx.x;
  const int bid = blockIdx.x;
  const int icb = bid % NICB;         // same icb -> same XCD (192 % 8 == 0)
  const int bgrp = bid / NICB;        // 0..10
  const int grp = l / 20;             // 0..3 (3 = idle lanes 60..63)
  const int q = l % 20;
  const int oc = q >> 1;              // 0..9
  const int half = q & 1;             // 0,1
  const int b = bgrp * 3 + grp;
  const bool valid = (grp < 3) && (b < B_);
  const int bb = (b < B_) ? b : 0;    // clamp for loads only

  float2 acc[4];
#pragma unroll
  for (int j = 0; j < 4; ++j) acc[j] = make_float2(0.f, 0.f);

  for (int k = 0; k < KI; ++k) {
    const int ic = icb * KI + k;

    // ---- weights w[ic][oc][0..7][half*8 .. +8) -> 32 float2 registers ----
    float2 w2[IDN][4];
    {
      const float* wp = wg + ((size_t)ic * OCN + oc) * (IDN * ODN) + half * ODH;
#pragma unroll
      for (int id = 0; id < IDN; ++id) {
        const float4 v0 = *(const float4*)(wp + id * ODN);
        const float4 v1 = *(const float4*)(wp + id * ODN + 4);
        w2[id][0] = make_float2(v0.x, v0.y);
        w2[id][1] = make_float2(v0.z, v0.w);
        w2[id][2] = make_float2(v1.x, v1.y);
        w2[id][3] = make_float2(v1.z, v1.w);
      }
    }

    // ---- x[b,ic,:] normalized over id ----
    float xn[IDN];
    {
      const float* xp = xg + ((size_t)bb * ICN + ic) * IDN;
      const float4 a0 = ((const float4*)xp)[0];
      const float4 a1 = ((const float4*)xp)[1];
      xn[0] = a0.x; xn[1] = a0.y; xn[2] = a0.z; xn[3] = a0.w;
      xn[4] = a1.x; xn[5] = a1.y; xn[6] = a1.z; xn[7] = a1.w;
      float s = 0.f;
#pragma unroll
      for (int i = 0; i < IDN; ++i) s += xn[i];
      const float r = __builtin_amdgcn_rcpf(s + EPS);
#pragma unroll
      for (int i = 0; i < IDN; ++i) xn[i] *= r;
    }

    // ---- NNMF iterations (cross-half sums via DPP, everything else in-lane) ----
    float2 h2[4];
#pragma unroll
    for (int j = 0; j < 4; ++j) h2[j] = make_float2(1.f / ODN, 1.f / ODN);

    for (int it = 0; it < NIT; ++it) {
      float2 hacc[4];
#pragma unroll
      for (int j = 0; j < 4; ++j) hacc[j] = make_float2(0.f, 0.f);
#pragma unroll
      for (int id = 0; id < IDN; ++id) {
        float2 d2 = f2_mul(h2[0], w2[id][0]);
        d2 = f2_fma(h2[1], w2[id][1], d2);
        d2 = f2_fma(h2[2], w2[id][2], d2);
        d2 = f2_fma(h2[3], w2[id][3], d2);
        const float pd = d2.x + d2.y;
        const float den = pd + lane_swap1(pd);          // full 16-od sum
        const float tc = xn[id] * __builtin_amdgcn_rcpf(den + EPS);
        const float2 t2 = make_float2(tc, tc);
#pragma unroll
        for (int j = 0; j < 4; ++j) hacc[j] = f2_fma(w2[id][j], t2, hacc[j]);
      }
      float2 s2 = make_float2(0.f, 0.f);
#pragma unroll
      for (int j = 0; j < 4; ++j) {
        h2[j] = f2_mul(h2[j], hacc[j]);
        s2.x += h2[j].x; s2.y += h2[j].y;
      }
      const float ps = s2.x + s2.y;
      const float hs = ps + lane_swap1(ps);             // full 16-od sum
      const float r = __builtin_amdgcn_rcpf(hs + EPS);
      const float2 r2 = make_float2(r, r);
#pragma unroll
      for (int j = 0; j < 4; ++j) h2[j] = f2_mul(h2[j], r2);
    }

    // ---- alpha = sum_id dot(h, w[id]) * xn[id], normalized over oc ----
    float ap = 0.f;
#pragma unroll
    for (int id = 0; id < IDN; ++id) {
      float2 d2 = f2_mul(h2[0], w2[id][0]);
      d2 = f2_fma(h2[1], w2[id][1], d2);
      d2 = f2_fma(h2[2], w2[id][2], d2);
      d2 = f2_fma(h2[3], w2[id][3], d2);
      ap = fmaf(d2.x + d2.y, xn[id], ap);
    }
    const float af = ap + lane_swap1(ap);               // full alpha(b,ic,oc)
    float asum = 0.f;
    const int gbase = grp * 20;
#pragma unroll
    for (int k2 = 0; k2 < OCN; ++k2) asum += __shfl(af, gbase + 2 * k2, 64);
    const float an = af * __builtin_amdgcn_rcpf(asum + EPS);
    const float2 an2 = make_float2(an, an);
#pragma unroll
    for (int j = 0; j < 4; ++j) acc[j] = f2_fma(h2[j], an2, acc[j]);
  }

  if (valid) {
    float* dst = outg + (bb * OCN + oc) * ODN + half * ODH;
#pragma unroll
    for (int j = 0; j < 4; ++j) {
      atomicAdd(dst + j * 2 + 0, acc[j].x);
      atomicAdd(dst + j * 2 + 1, acc[j].y);
    }
  }
}

extern "C" void kernel_launch(void* const* d_in, const int* in_sizes, int n_in,
                              void* d_out, int out_size, void* d_ws, size_t ws_size,
                              hipStream_t stream) {
  const float* x = (const float*)d_in[0];
  const float* w = (const float*)d_in[1];
  float* out = (float*)d_out;

  hipMemsetAsync(out, 0, OUTN * sizeof(float), stream);
  caps_main<<<NBLK, 64, 0, stream>>>(x, w, out);
}

// Round 5
// 92.081 us; speedup vs baseline: 5.0254x; 1.6609x over previous
//
#include <hip/hip_runtime.h>

#define B_   32
#define ICN  1152
#define OCN  10
#define IDN  8
#define ODN  16
#define ODH  8                  // od half per lane (split across lane pairs)
#define NIT  5
#define EPS  1e-20f
#define OUTN (B_ * OCN * ODN)   // 5120
#define KI   3                  // input caps accumulated per block
#define NICB (ICN / KI)         // 384
#define BGRP 11                 // ceil(32 / 3 b's per wave)
#define NBLK (NICB * BGRP)      // 4224 one-wave blocks
#define RG   8                  // stage-A rows per group
#define NGRP (NICB / RG)        // 48

// non-rematerializable register pin: forces the value to live in a VGPR
#define KEEP(x) asm volatile("" : "+v"(x))

// swap with neighbor lane (l ^ 1) via DPP quad_perm [1,0,3,2] — VALU pipe, no DS
__device__ __forceinline__ float lane_swap1(float x) {
  int i = __builtin_bit_cast(int, x);
  int r = __builtin_amdgcn_mov_dpp(i, 0xB1, 0xF, 0xF, false);
  return __builtin_bit_cast(float, r);
}

__device__ __forceinline__ float2 f2_fma(const float2 a, const float2 b, const float2 c) {
  float2 r;
  r.x = fmaf(a.x, b.x, c.x);
  r.y = fmaf(a.y, b.y, c.y);
  return r;
}
__device__ __forceinline__ float2 f2_mul(const float2 a, const float2 b) {
  float2 r; r.x = a.x * b.x; r.y = a.y * b.y; return r;
}

// ---------------------------------------------------------------------------
// One wave = 3 (b) groups x 10 oc x 2 od-halves (lanes 60..63 idle).
// Each lane PINS its 8x8 weight half-slice in 64 VGPRs (inline-asm keep, so
// the compiler cannot re-sink the loads into the loop). Cross-half sums are
// DPP quad-perm swaps. Block accumulates KI=3 ics, then stores its disjoint
// 480-float slice to ws[icb] (coalesced, no atomics). Tree-reduce follows.
// Same-icb blocks are NICB apart in blockIdx (384 % 8 == 0 -> same XCD, so
// the 11 bgrps sharing w[icb-range] hit the same L2).
// ---------------------------------------------------------------------------
__global__ __launch_bounds__(64, 2) void caps_main(
    const float* __restrict__ xg, const float* __restrict__ wg,
    float* __restrict__ ws, float* __restrict__ outg, int atomic_out) {
  const int l = threadIdx.x;
  const int bid = blockIdx.x;
  const int icb = bid % NICB;
  const int bgrp = bid / NICB;        // 0..10
  const int grp = l / 20;             // 0..3 (3 = idle lanes 60..63)
  const int q = l % 20;
  const int oc = q >> 1;              // 0..9
  const int half = q & 1;             // 0,1
  const int b = bgrp * 3 + grp;
  const bool valid = (grp < 3) && (b < B_);
  const int bb = (b < B_) ? b : 0;    // clamp for loads only

  float2 acc[4];
#pragma unroll
  for (int j = 0; j < 4; ++j) acc[j] = make_float2(0.f, 0.f);

  for (int k = 0; k < KI; ++k) {
    const int ic = icb * KI + k;

    // ---- weights w[ic][oc][0..7][half*8 .. +8) -> 32 float2, PINNED ----
    float2 w2[IDN][4];
    {
      const float* wp = wg + ((size_t)ic * OCN + oc) * (IDN * ODN) + half * ODH;
#pragma unroll
      for (int id = 0; id < IDN; ++id) {
        const float4 v0 = *(const float4*)(wp + id * ODN);
        const float4 v1 = *(const float4*)(wp + id * ODN + 4);
        w2[id][0] = make_float2(v0.x, v0.y);
        w2[id][1] = make_float2(v0.z, v0.w);
        w2[id][2] = make_float2(v1.x, v1.y);
        w2[id][3] = make_float2(v1.z, v1.w);
      }
#pragma unroll
      for (int id = 0; id < IDN; ++id) {
#pragma unroll
        for (int j = 0; j < 4; ++j) { KEEP(w2[id][j].x); KEEP(w2[id][j].y); }
      }
    }

    // ---- x[b,ic,:] normalized over id ----
    float xn[IDN];
    {
      const float* xp = xg + ((size_t)bb * ICN + ic) * IDN;
      const float4 a0 = ((const float4*)xp)[0];
      const float4 a1 = ((const float4*)xp)[1];
      xn[0] = a0.x; xn[1] = a0.y; xn[2] = a0.z; xn[3] = a0.w;
      xn[4] = a1.x; xn[5] = a1.y; xn[6] = a1.z; xn[7] = a1.w;
      float s = 0.f;
#pragma unroll
      for (int i = 0; i < IDN; ++i) s += xn[i];
      const float r = __builtin_amdgcn_rcpf(s + EPS);
#pragma unroll
      for (int i = 0; i < IDN; ++i) xn[i] *= r;
#pragma unroll
      for (int i = 0; i < IDN; ++i) KEEP(xn[i]);
    }

    // ---- NNMF iterations (cross-half sums via DPP, all else in-lane) ----
    float2 h2[4];
#pragma unroll
    for (int j = 0; j < 4; ++j) h2[j] = make_float2(1.f / ODN, 1.f / ODN);

    for (int it = 0; it < NIT; ++it) {
      float2 hacc[4];
#pragma unroll
      for (int j = 0; j < 4; ++j) hacc[j] = make_float2(0.f, 0.f);
#pragma unroll
      for (int id = 0; id < IDN; ++id) {
        float2 d2 = f2_mul(h2[0], w2[id][0]);
        d2 = f2_fma(h2[1], w2[id][1], d2);
        d2 = f2_fma(h2[2], w2[id][2], d2);
        d2 = f2_fma(h2[3], w2[id][3], d2);
        const float pd = d2.x + d2.y;
        const float den = pd + lane_swap1(pd);          // full 16-od sum
        const float tc = xn[id] * __builtin_amdgcn_rcpf(den + EPS);
        const float2 t2 = make_float2(tc, tc);
#pragma unroll
        for (int j = 0; j < 4; ++j) hacc[j] = f2_fma(w2[id][j], t2, hacc[j]);
      }
      float2 s2 = make_float2(0.f, 0.f);
#pragma unroll
      for (int j = 0; j < 4; ++j) {
        h2[j] = f2_mul(h2[j], hacc[j]);
        s2.x += h2[j].x; s2.y += h2[j].y;
      }
      const float ps = s2.x + s2.y;
      const float hs = ps + lane_swap1(ps);             // full 16-od sum
      const float r = __builtin_amdgcn_rcpf(hs + EPS);
      const float2 r2 = make_float2(r, r);
#pragma unroll
      for (int j = 0; j < 4; ++j) h2[j] = f2_mul(h2[j], r2);
    }

    // ---- alpha = sum_id dot(h, w[id]) * xn[id], normalized over oc ----
    float ap = 0.f;
#pragma unroll
    for (int id = 0; id < IDN; ++id) {
      float2 d2 = f2_mul(h2[0], w2[id][0]);
      d2 = f2_fma(h2[1], w2[id][1], d2);
      d2 = f2_fma(h2[2], w2[id][2], d2);
      d2 = f2_fma(h2[3], w2[id][3], d2);
      ap = fmaf(d2.x + d2.y, xn[id], ap);
    }
    const float af = ap + lane_swap1(ap);               // full alpha(b,ic,oc)
    float asum = 0.f;
    const int gbase = grp * 20;
#pragma unroll
    for (int k2 = 0; k2 < OCN; ++k2) asum += __shfl(af, gbase + 2 * k2, 64);
    const float an = af * __builtin_amdgcn_rcpf(asum + EPS);
    const float2 an2 = make_float2(an, an);
#pragma unroll
    for (int j = 0; j < 4; ++j) acc[j] = f2_fma(h2[j], an2, acc[j]);
  }

  if (valid) {
    if (!atomic_out) {
      // disjoint slice: ws[icb][b][oc][od-half] — coalesced within the wave
      float* dst = ws + (size_t)icb * OUTN + (bb * OCN + oc) * ODN + half * ODH;
      float4 v0, v1;
      v0.x = acc[0].x; v0.y = acc[0].y; v0.z = acc[1].x; v0.w = acc[1].y;
      v1.x = acc[2].x; v1.y = acc[2].y; v1.z = acc[3].x; v1.w = acc[3].y;
      ((float4*)dst)[0] = v0;
      ((float4*)dst)[1] = v1;
    } else {
      float* dst = outg + (bb * OCN + oc) * ODN + half * ODH;
#pragma unroll
      for (int j = 0; j < 4; ++j) {
        atomicAdd(dst + j * 2 + 0, acc[j].x);
        atomicAdd(dst + j * 2 + 1, acc[j].y);
      }
    }
  }
}

// ---------------------------------------------------------------------------
// Tree reduce over the 384 ic-block rows: stage A sums 8 rows -> 48 partial
// rows; stage B sums the 48 and writes out (full overwrite, no atomics).
// ---------------------------------------------------------------------------
__global__ void caps_reduceA(const float* __restrict__ wsA, float* __restrict__ wsB) {
  const int j = blockIdx.x * 256 + threadIdx.x;
  const int g = blockIdx.y;
  float s = 0.f;
#pragma unroll
  for (int r = 0; r < RG; ++r) s += wsA[(size_t)(g * RG + r) * OUTN + j];
  wsB[(size_t)g * OUTN + j] = s;
}

__global__ void caps_reduceB(const float* __restrict__ wsB, float* __restrict__ outg) {
  const int j = blockIdx.x * 256 + threadIdx.x;
  float s = 0.f;
#pragma unroll
  for (int g = 0; g < NGRP; ++g) s += wsB[(size_t)g * OUTN + j];
  outg[j] = s;
}

extern "C" void kernel_launch(void* const* d_in, const int* in_sizes, int n_in,
                              void* d_out, int out_size, void* d_ws, size_t ws_size,
                              hipStream_t stream) {
  const float* x = (const float*)d_in[0];
  const float* w = (const float*)d_in[1];
  float* out = (float*)d_out;
  float* wsA = (float*)d_ws;
  float* wsB = wsA + (size_t)NICB * OUTN;

  const size_t need = (size_t)(NICB + NGRP) * OUTN * sizeof(float);  // 8.9 MB

  if (ws_size >= need) {
    caps_main<<<NBLK, 64, 0, stream>>>(x, w, wsA, out, 0);
    caps_reduceA<<<dim3(OUTN / 256, NGRP), 256, 0, stream>>>(wsA, wsB);
    caps_reduceB<<<OUTN / 256, 256, 0, stream>>>(wsB, out);
  } else {
    hipMemsetAsync(out, 0, OUTN * sizeof(float), stream);
    caps_main<<<NBLK, 64, 0, stream>>>(x, w, nullptr, out, 1);
  }
}